// Round 3
// baseline (232.580 us; speedup 1.0000x reference)
//
#include <hip/hip_runtime.h>

// Problem constants (fixed by reference setup_inputs)
#define BATCH 8
#define NPTS  4096   // N == M == 4096
#define KD    64
#define MQ    8      // m-strips: each block walks 512 cols = 4 tiles of 128
#define WALK  4
#define FINF  3.0e38f

typedef float f32x4 __attribute__((ext_vector_type(4)));
typedef float f32x2 __attribute__((ext_vector_type(2)));
typedef short s16x8 __attribute__((ext_vector_type(8)));

__device__ __forceinline__ unsigned int f2bf(float f) {
  // round-to-nearest-even fp32 -> bf16 (inputs finite)
  unsigned int u = __float_as_uint(f);
  u += 0x7FFFu + ((u >> 16) & 1u);
  return u >> 16;
}

__device__ __forceinline__ void stage16(const void* g, void* l) {
  // async global->LDS, 16B/lane; LDS dst = wave-uniform base + lane*16
  __builtin_amdgcn_global_load_lds((const __attribute__((address_space(1))) void*)g,
                                   (__attribute__((address_space(3))) void*)l, 16, 0, 0);
}

// ---------------------------------------------------------------------------
// Prepass: convert X,Y (fp32 [32768][64]) to bf16 packed (uint [32768][32])
// and compute exact fp32 squared norms. 32 threads per row, 2 floats/thread.
__global__ __launch_bounds__(256)
void prep_kernel(const float* __restrict__ X, const float* __restrict__ Y,
                 unsigned int* __restrict__ Xbf, unsigned int* __restrict__ Ybf,
                 float* __restrict__ x2, float* __restrict__ y2) {
  int gid = blockIdx.x * 256 + threadIdx.x;
  int row = gid >> 5;
  int ki  = gid & 31;
  bool isX = row < BATCH * NPTS;
  int r2 = row & (BATCH * NPTS - 1);
  const float* src = isX ? X : Y;
  f32x2 v = *(const f32x2*)(src + (size_t)r2 * KD + ki * 2);
  float s = v[0] * v[0] + v[1] * v[1];
  #pragma unroll
  for (int m = 16; m >= 1; m >>= 1) s += __shfl_xor(s, m, 64);  // stays in 32-lane half
  unsigned int packed = (f2bf(v[1]) << 16) | f2bf(v[0]);
  (isX ? Xbf : Ybf)[r2 * 32 + ki] = packed;
  if (ki == 0) (isX ? x2 : y2)[r2] = s;
}

// ---------------------------------------------------------------------------
// Main: block = (mq, ntile, b). 128 rows x 512 cols (4 m-tiles of 128).
// X fragments in registers for the whole walk; Y double-buffered in LDS via
// global_load_lds with XOR-swizzled layout. Waves = 4 column strips of 32.
// Per iteration: y2 loads FIRST, then prefetch (keeps prefetch async: the
// epilogue's y2 wait is vmcnt(4), not vmcnt(0)).
__global__ __launch_bounds__(256, 3)
void chamfer_main(const unsigned short* __restrict__ Xbf,
                  const unsigned short* __restrict__ Ybf,
                  const float* __restrict__ x2g, const float* __restrict__ y2g,
                  float* __restrict__ rowpart,   // [MQ][B*N] min over strip cols (sq)
                  float* __restrict__ colpart) { // [32][B*M] min over ntile rows (sq)
  __shared__ __align__(16) unsigned short Xs[128 * 64];      // 16 KB
  __shared__ __align__(16) unsigned short Ys[2][128 * 64];   // 32 KB
  __shared__ float l_red[4 * 128];                           // 2 KB

  const int mq = blockIdx.x, ntile = blockIdx.y, b = blockIdx.z;
  const int n0 = ntile * 128;
  const int mbase = mq * 512;
  const int t = threadIdx.x, w = t >> 6, lane = t & 63, c = lane & 15, q = lane >> 4;

  // staging source offset within a 1KB (8-row) block: row=lane>>3, chunk=(lane&7)^(lane>>3)
  const int l8 = lane >> 3;
  const int lane_off = l8 * 128 + (((lane & 7) ^ l8) << 4);

  const char* Xg  = (const char*)(Xbf + (size_t)(b * NPTS + n0) * KD);
  const char* Yg0 = (const char*)(Ybf + (size_t)(b * NPTS + mbase) * KD);

  // Prologue: stage X tile + Y tile 0 (4 x 1KB per wave each)
  #pragma unroll
  for (int k = 0; k < 4; ++k) {
    int blockoff = (k * 32 + w * 8) * 128;
    int ldsoff   = (k * 256 + w * 64) * 16;
    stage16(Xg  + blockoff + lane_off, (char*)Xs    + ldsoff);
    stage16(Yg0 + blockoff + lane_off, (char*)Ys[0] + ldsoff);
  }

  // x2 fragment (rows i*16 + q*4 + r), fp32, L2-hot
  f32x4 x2r[8];
  const float* x2b = x2g + b * NPTS + n0;
  #pragma unroll
  for (int i = 0; i < 8; ++i) x2r[i] = *(const f32x4*)(x2b + i * 16 + q * 4);

  __syncthreads();  // drains the global_load_lds (vmcnt 0 at barrier)

  // X fragments -> registers (swizzled ds_read_b128, conflict-free)
  const int cx = c & 7;
  s16x8 xf[8][2];
  #pragma unroll
  for (int i = 0; i < 8; ++i)
    #pragma unroll
    for (int ks = 0; ks < 2; ++ks)
      xf[i][ks] = *(const s16x8*)&Xs[(i * 16 + c) * 64 + ((((ks << 2) + q) ^ cx) << 3)];

  float rm[8][4];
  #pragma unroll
  for (int i = 0; i < 8; ++i)
    #pragma unroll
    for (int r = 0; r < 4; ++r) rm[i][r] = FINF;

  const float* y2b = y2g + b * NPTS + mbase;
  float* colrow = colpart + (size_t)(ntile * 8 + b) * NPTS + mbase;
  const f32x4 zacc = {0.f, 0.f, 0.f, 0.f};

  #pragma unroll
  for (int tt = 0; tt < WALK; ++tt) {
    const unsigned short* cur = Ys[tt & 1];
    // y2 for this wave's two 16-col groups: ISSUE BEFORE the prefetch so the
    // epilogue's wait on y2 leaves the prefetch in flight (vmcnt(4), not 0).
    float y2c0 = y2b[tt * 128 + w * 32 + c];
    float y2c1 = y2b[tt * 128 + w * 32 + 16 + c];

    if (tt < WALK - 1) {  // async-prefetch next Y tile into the other buffer
      const char* Ygt = Yg0 + (size_t)(tt + 1) * 128 * 128;
      unsigned short* nb = Ys[(tt + 1) & 1];
      #pragma unroll
      for (int k = 0; k < 4; ++k)
        stage16(Ygt + (k * 32 + w * 8) * 128 + lane_off,
                (char*)nb + (k * 256 + w * 64) * 16);
    }

    // j-split: halves live accumulator (32 AGPRs) and yf (8 VGPRs)
    #pragma unroll
    for (int j = 0; j < 2; ++j) {
      s16x8 yf0 = *(const s16x8*)&cur[(w * 32 + j * 16 + c) * 64 + ((q ^ cx) << 3)];
      s16x8 yf1 = *(const s16x8*)&cur[(w * 32 + j * 16 + c) * 64 + (((4 + q) ^ cx) << 3)];
      f32x4 acc[8];
      #pragma unroll
      for (int i = 0; i < 8; ++i) {
        f32x4 a0 = __builtin_amdgcn_mfma_f32_16x16x32_bf16(xf[i][0], yf0, zacc, 0, 0, 0);
        acc[i] = __builtin_amdgcn_mfma_f32_16x16x32_bf16(xf[i][1], yf1, a0, 0, 0, 0);
      }
      float y2c = (j == 0) ? y2c0 : y2c1;
      float cm = FINF;
      #pragma unroll
      for (int i = 0; i < 8; ++i)
        #pragma unroll
        for (int r = 0; r < 4; ++r) {
          float v = acc[i][r];
          rm[i][r] = fminf(rm[i][r], fmaf(-2.f, v, y2c));
          cm = fminf(cm, fmaf(-2.f, v, x2r[i][r]));
        }
      // col-min: reduce over the 4 q-groups (rows), then store (cols wave-private)
      cm = fminf(cm, __shfl_xor(cm, 16, 64));
      cm = fminf(cm, __shfl_xor(cm, 32, 64));
      if (q == j) colrow[tt * 128 + w * 32 + j * 16 + c] = cm + y2c;
    }
    __syncthreads();  // buffer swap barrier (prefetch had MFMA+epilogue to land)
  }

  // Row-min epilogue (once per block): reduce over c within q-group...
  #pragma unroll
  for (int msk = 1; msk <= 8; msk <<= 1)
    #pragma unroll
    for (int i = 0; i < 8; ++i)
      #pragma unroll
      for (int r = 0; r < 4; ++r)
        rm[i][r] = fminf(rm[i][r], __shfl_xor(rm[i][r], msk, 64));
  // ...then across the 4 waves via LDS. Lane c owns (i=c>>1, r=(c&1)*2+{0,1}).
  {
    int ii = c >> 1, rb = (c & 1) * 2;
    l_red[w * 128 + ii * 16 + q * 4 + rb]     = rm[ii][rb];
    l_red[w * 128 + ii * 16 + q * 4 + rb + 1] = rm[ii][rb + 1];
  }
  __syncthreads();
  if (t < 128) {
    float v = fminf(fminf(l_red[t], l_red[128 + t]),
                    fminf(l_red[256 + t], l_red[384 + t]));
    rowpart[mq * (BATCH * NPTS) + b * NPTS + n0 + t] = v + x2b[t];
  }
}

// ---------------------------------------------------------------------------
// Final: min over partials, sqrt, mean. 128 blocks x 256 = 32768 threads,
// thread i handles row i (min of MQ) and col i (min of 32).
__global__ __launch_bounds__(256)
void reduce_kernel(const float* __restrict__ rowpart, const float* __restrict__ colpart,
                   float* __restrict__ out) {
  int i = blockIdx.x * 256 + threadIdx.x;
  const int TOT = BATCH * NPTS;
  float rv = FINF;
  #pragma unroll
  for (int s = 0; s < MQ; ++s) rv = fminf(rv, rowpart[s * TOT + i]);
  float s0 = sqrtf(fmaxf(rv, 0.f));
  float cv = FINF;
  #pragma unroll
  for (int nt = 0; nt < 32; ++nt) cv = fminf(cv, colpart[nt * TOT + i]);
  s0 += sqrtf(fmaxf(cv, 0.f));
  #pragma unroll
  for (int m = 32; m >= 1; m >>= 1) s0 += __shfl_xor(s0, m, 64);
  __shared__ float wsum[4];
  if ((threadIdx.x & 63) == 0) wsum[threadIdx.x >> 6] = s0;
  __syncthreads();
  if (threadIdx.x == 0)
    atomicAdd(out, (wsum[0] + wsum[1] + wsum[2] + wsum[3]) * (1.0f / (float)TOT));
}

// ---------------------------------------------------------------------------
extern "C" void kernel_launch(void* const* d_in, const int* in_sizes, int n_in,
                              void* d_out, int out_size, void* d_ws, size_t ws_size,
                              hipStream_t stream) {
  const float* X = (const float*)d_in[0];  // [B, N, 64] fp32
  const float* Y = (const float*)d_in[1];  // [B, M, 64] fp32
  float* out = (float*)d_out;

  // Workspace layout (bytes):
  //   Xbf 4MB | Ybf 4MB | x2 128KB | y2 128KB | rowpart 1MB | colpart 4MB
  char* ws = (char*)d_ws;
  unsigned int* Xbf = (unsigned int*)ws;                       // packed bf16 pairs
  unsigned int* Ybf = (unsigned int*)(ws + (4u << 20));
  float* x2 = (float*)(ws + (8u << 20));
  float* y2 = (float*)(ws + (8u << 20) + (128u << 10));
  float* rowpart = (float*)(ws + (8u << 20) + (256u << 10));
  float* colpart = (float*)(ws + (9u << 20) + (256u << 10));

  hipMemsetAsync(out, 0, sizeof(float), stream);

  // Prepass: both inputs, 32 threads/row.
  prep_kernel<<<dim3(2 * BATCH * NPTS * 32 / 256), dim3(256), 0, stream>>>(
      X, Y, Xbf, Ybf, x2, y2);

  // Main: (mq=8, ntile=32, b=8) = 2048 blocks (~3 resident/CU, continuous refill).
  chamfer_main<<<dim3(MQ, 32, 8), dim3(256), 0, stream>>>(
      (const unsigned short*)Xbf, (const unsigned short*)Ybf, x2, y2, rowpart, colpart);

  // Final min/sqrt/mean.
  reduce_kernel<<<dim3(BATCH * NPTS / 256), dim3(256), 0, stream>>>(rowpart, colpart, out);
}

// Round 4
// 125.164 us; speedup vs baseline: 1.8582x; 1.8582x over previous
//
#include <hip/hip_runtime.h>

// Problem constants (fixed by reference setup_inputs)
#define BATCH 8
#define NPTS  4096   // N == M == 4096
#define KD    64
#define MQ    8      // m-strips: each block walks 512 cols = 4 tiles of 128
#define WALK  4
#define FINF  3.0e38f

typedef float f32x4 __attribute__((ext_vector_type(4)));
typedef float f32x2 __attribute__((ext_vector_type(2)));
typedef short s16x8 __attribute__((ext_vector_type(8)));

__device__ __forceinline__ unsigned int f2bf(float f) {
  // round-to-nearest-even fp32 -> bf16 (inputs finite)
  unsigned int u = __float_as_uint(f);
  u += 0x7FFFu + ((u >> 16) & 1u);
  return u >> 16;
}

__device__ __forceinline__ void stage16(const void* g, void* l) {
  // async global->LDS, 16B/lane; LDS dst = wave-uniform base + lane*16
  __builtin_amdgcn_global_load_lds((const __attribute__((address_space(1))) void*)g,
                                   (__attribute__((address_space(3))) void*)l, 16, 0, 0);
}

// ---------------------------------------------------------------------------
// Prepass: convert X,Y (fp32 [32768][64]) to bf16 packed (uint [32768][32])
// and compute exact fp32 squared norms. 32 threads per row, 2 floats/thread.
__global__ __launch_bounds__(256)
void prep_kernel(const float* __restrict__ X, const float* __restrict__ Y,
                 unsigned int* __restrict__ Xbf, unsigned int* __restrict__ Ybf,
                 float* __restrict__ x2, float* __restrict__ y2) {
  int gid = blockIdx.x * 256 + threadIdx.x;
  int row = gid >> 5;
  int ki  = gid & 31;
  bool isX = row < BATCH * NPTS;
  int r2 = row & (BATCH * NPTS - 1);
  const float* src = isX ? X : Y;
  f32x2 v = *(const f32x2*)(src + (size_t)r2 * KD + ki * 2);
  float s = v[0] * v[0] + v[1] * v[1];
  #pragma unroll
  for (int m = 16; m >= 1; m >>= 1) s += __shfl_xor(s, m, 64);  // stays in 32-lane half
  unsigned int packed = (f2bf(v[1]) << 16) | f2bf(v[0]);
  (isX ? Xbf : Ybf)[r2 * 32 + ki] = packed;
  if (ki == 0) (isX ? x2 : y2)[r2] = s;
}

// ---------------------------------------------------------------------------
// Main: block = (mq, ntile, b). 128 rows x 512 cols (4 m-tiles of 128).
// Waves in 2x2: wave tile 64 rows x 64 cols per m-tile. Register budget is
// sized to ~120 live VGPRs (xf 32 + x2r 16 + rm 16 + acc 16 + yf 8 + temps)
// so NOTHING spills under the (256,3) cap — rounds 2/3 spilled xf/rm to
// scratch (VGPR_Count 84, WRITE_SIZE 600 MB) and were scratch-bound.
// Y double-buffered in LDS via global_load_lds, XOR-swizzled. y2 loads issue
// BEFORE the prefetch so the epilogue's y2 wait is vmcnt(4), not vmcnt(0).
__global__ __launch_bounds__(256, 3)
void chamfer_main(const unsigned short* __restrict__ Xbf,
                  const unsigned short* __restrict__ Ybf,
                  const float* __restrict__ x2g, const float* __restrict__ y2g,
                  float* __restrict__ rowpart,   // [MQ][B*N] min over strip cols (sq)
                  float* __restrict__ colpart) { // [32][B*M] min over ntile rows (sq)
  __shared__ __align__(16) unsigned short Xs[128 * 64];      // 16 KB (reused as l_redf)
  __shared__ __align__(16) unsigned short Ys[2][128 * 64];   // 32 KB
  __shared__ float l_cred[2 * 512];                          // 4 KB: [rowgroup][strip col]

  const int mq = blockIdx.x, ntile = blockIdx.y, b = blockIdx.z;
  const int n0 = ntile * 128;
  const int mbase = mq * 512;
  const int t = threadIdx.x, w = t >> 6, lane = t & 63, c = lane & 15, q = lane >> 4;
  const int wr = (w >> 1) * 64, wc = (w & 1) * 64, rg = w >> 1;

  // staging source offset within a 1KB (8-row) block: row=lane>>3, chunk=(lane&7)^(lane>>3)
  const int l8 = lane >> 3;
  const int lane_off = l8 * 128 + (((lane & 7) ^ l8) << 4);

  const char* Xg  = (const char*)(Xbf + (size_t)(b * NPTS + n0) * KD);
  const char* Yg0 = (const char*)(Ybf + (size_t)(b * NPTS + mbase) * KD);

  // Prologue: stage X tile + Y tile 0 (4 x 1KB per wave each)
  #pragma unroll
  for (int k = 0; k < 4; ++k) {
    int blockoff = (k * 32 + w * 8) * 128;
    int ldsoff   = (k * 256 + w * 64) * 16;
    stage16(Xg  + blockoff + lane_off, (char*)Xs    + ldsoff);
    stage16(Yg0 + blockoff + lane_off, (char*)Ys[0] + ldsoff);
  }

  // x2 fragment (rows wr + i*16 + q*4 + r), fp32, L2-hot. 16 VGPRs.
  const float* x2b = x2g + b * NPTS + n0;
  f32x4 x2r[4];
  #pragma unroll
  for (int i = 0; i < 4; ++i) x2r[i] = *(const f32x4*)(x2b + wr + i * 16 + q * 4);

  __syncthreads();  // drains the global_load_lds (vmcnt 0 at barrier)

  // X fragments -> registers (swizzled ds_read_b128, conflict-free). 32 VGPRs.
  const int cx = c & 7;
  s16x8 xf[4][2];
  #pragma unroll
  for (int i = 0; i < 4; ++i)
    #pragma unroll
    for (int ks = 0; ks < 2; ++ks)
      xf[i][ks] = *(const s16x8*)&Xs[(wr + i * 16 + c) * 64 + ((((ks << 2) + q) ^ cx) << 3)];

  float rm[4][4];
  #pragma unroll
  for (int i = 0; i < 4; ++i)
    #pragma unroll
    for (int r = 0; r < 4; ++r) rm[i][r] = FINF;

  const float* y2b = y2g + b * NPTS + mbase;
  const f32x4 zacc = {0.f, 0.f, 0.f, 0.f};

  #pragma unroll
  for (int tt = 0; tt < WALK; ++tt) {
    const unsigned short* cur = Ys[tt & 1];

    // y2 for this wave's 4 col groups — BEFORE the prefetch (keeps it async).
    float y2c[4];
    #pragma unroll
    for (int j = 0; j < 4; ++j) y2c[j] = y2b[tt * 128 + wc + j * 16 + c];

    if (tt < WALK - 1) {  // async-prefetch next Y tile into the other buffer
      const char* Ygt = Yg0 + (size_t)(tt + 1) * 128 * 128;
      unsigned short* nb = Ys[(tt + 1) & 1];
      #pragma unroll
      for (int k = 0; k < 4; ++k)
        stage16(Ygt + (k * 32 + w * 8) * 128 + lane_off,
                (char*)nb + (k * 256 + w * 64) * 16);
    }

    float cmj[4];
    #pragma unroll
    for (int j = 0; j < 4; ++j) {
      const unsigned short* yrow = &cur[(wc + j * 16 + c) * 64];
      s16x8 yf0 = *(const s16x8*)&yrow[(q ^ cx) << 3];
      s16x8 yf1 = *(const s16x8*)&yrow[((4 + q) ^ cx) << 3];
      f32x4 acc[4];
      #pragma unroll
      for (int i = 0; i < 4; ++i) {
        f32x4 a0 = __builtin_amdgcn_mfma_f32_16x16x32_bf16(xf[i][0], yf0, zacc, 0, 0, 0);
        acc[i] = __builtin_amdgcn_mfma_f32_16x16x32_bf16(xf[i][1], yf1, a0, 0, 0, 0);
      }
      float cm = FINF;
      #pragma unroll
      for (int i = 0; i < 4; ++i)
        #pragma unroll
        for (int r = 0; r < 4; ++r) {
          float v = acc[i][r];
          rm[i][r] = fminf(rm[i][r], fmaf(-2.f, v, y2c[j]));
          cm = fminf(cm, fmaf(-2.f, v, x2r[i][r]));
        }
      // col-min over this wave's 64 rows: reduce across the 4 q-groups
      cm = fminf(cm, __shfl_xor(cm, 16, 64));
      cm = fminf(cm, __shfl_xor(cm, 32, 64));
      cmj[j] = cm;
    }
    // quad q stores col group j==q: one ds_write, 64 consecutive floats/wave
    float cmq = (q == 0) ? cmj[0] : (q == 1) ? cmj[1] : (q == 2) ? cmj[2] : cmj[3];
    l_cred[rg * 512 + tt * 128 + wc + q * 16 + c] = cmq;

    __syncthreads();  // buffer swap barrier (prefetch had MFMA+epilogue to land)
  }

  // Row-min: reduce over the 16 c-lanes within each q-group...
  #pragma unroll
  for (int msk = 1; msk <= 8; msk <<= 1)
    #pragma unroll
    for (int i = 0; i < 4; ++i)
      #pragma unroll
      for (int r = 0; r < 4; ++r)
        rm[i][r] = fminf(rm[i][r], __shfl_xor(rm[i][r], msk, 64));
  // ...then store per-wave row-mins to LDS (literal indices — no dynamic
  // register-array indexing, which forced scratch lowering in rounds 2/3).
  float* l_redf = (float*)Xs;  // Xs is dead after the prologue xf reads
  if (c == 0) {
    #pragma unroll
    for (int i = 0; i < 4; ++i) {
      f32x4 v = {rm[i][0], rm[i][1], rm[i][2], rm[i][3]};
      *(f32x4*)&l_redf[w * 64 + i * 16 + q * 4] = v;
    }
  }
  __syncthreads();

  if (t < 128) {
    // combine the 2 col-group waves of each row group, add x2, store
    int g = t >> 6, lr = t & 63;
    float v = fminf(l_redf[(g * 2) * 64 + lr], l_redf[(g * 2 + 1) * 64 + lr]);
    rowpart[mq * (BATCH * NPTS) + b * NPTS + n0 + t] = v + x2b[t];
  } else {
    // combine the 2 row groups for each of the 512 strip cols, add y2, store
    float* colrow = colpart + (size_t)(ntile * 8 + b) * NPTS + mbase;
    int ct = t - 128;
    #pragma unroll
    for (int u = 0; u < 4; ++u) {
      int cc = ct + u * 128;
      float v = fminf(l_cred[cc], l_cred[512 + cc]);
      colrow[cc] = v + y2b[cc];
    }
  }
}

// ---------------------------------------------------------------------------
// Final: min over partials, sqrt, mean. 128 blocks x 256 = 32768 threads,
// thread i handles row i (min of MQ) and col i (min of 32).
__global__ __launch_bounds__(256)
void reduce_kernel(const float* __restrict__ rowpart, const float* __restrict__ colpart,
                   float* __restrict__ out) {
  int i = blockIdx.x * 256 + threadIdx.x;
  const int TOT = BATCH * NPTS;
  float rv = FINF;
  #pragma unroll
  for (int s = 0; s < MQ; ++s) rv = fminf(rv, rowpart[s * TOT + i]);
  float s0 = sqrtf(fmaxf(rv, 0.f));
  float cv = FINF;
  #pragma unroll
  for (int nt = 0; nt < 32; ++nt) cv = fminf(cv, colpart[nt * TOT + i]);
  s0 += sqrtf(fmaxf(cv, 0.f));
  #pragma unroll
  for (int m = 32; m >= 1; m >>= 1) s0 += __shfl_xor(s0, m, 64);
  __shared__ float wsum[4];
  if ((threadIdx.x & 63) == 0) wsum[threadIdx.x >> 6] = s0;
  __syncthreads();
  if (threadIdx.x == 0)
    atomicAdd(out, (wsum[0] + wsum[1] + wsum[2] + wsum[3]) * (1.0f / (float)TOT));
}

// ---------------------------------------------------------------------------
extern "C" void kernel_launch(void* const* d_in, const int* in_sizes, int n_in,
                              void* d_out, int out_size, void* d_ws, size_t ws_size,
                              hipStream_t stream) {
  const float* X = (const float*)d_in[0];  // [B, N, 64] fp32
  const float* Y = (const float*)d_in[1];  // [B, M, 64] fp32
  float* out = (float*)d_out;

  // Workspace layout (bytes):
  //   Xbf 4MB | Ybf 4MB | x2 128KB | y2 128KB | rowpart 1MB | colpart 4MB
  char* ws = (char*)d_ws;
  unsigned int* Xbf = (unsigned int*)ws;                       // packed bf16 pairs
  unsigned int* Ybf = (unsigned int*)(ws + (4u << 20));
  float* x2 = (float*)(ws + (8u << 20));
  float* y2 = (float*)(ws + (8u << 20) + (128u << 10));
  float* rowpart = (float*)(ws + (8u << 20) + (256u << 10));
  float* colpart = (float*)(ws + (9u << 20) + (256u << 10));

  hipMemsetAsync(out, 0, sizeof(float), stream);

  // Prepass: both inputs, 32 threads/row.
  prep_kernel<<<dim3(2 * BATCH * NPTS * 32 / 256), dim3(256), 0, stream>>>(
      X, Y, Xbf, Ybf, x2, y2);

  // Main: (mq=8, ntile=32, b=8) = 2048 blocks, 3 resident/CU (LDS-capped).
  chamfer_main<<<dim3(MQ, 32, 8), dim3(256), 0, stream>>>(
      (const unsigned short*)Xbf, (const unsigned short*)Ybf, x2, y2, rowpart, colpart);

  // Final min/sqrt/mean.
  reduce_kernel<<<dim3(BATCH * NPTS / 256), dim3(256), 0, stream>>>(rowpart, colpart, out);
}

// Round 5
// 106.253 us; speedup vs baseline: 2.1889x; 1.1780x over previous
//
#include <hip/hip_runtime.h>

// Problem constants (fixed by reference setup_inputs)
#define BATCH 8
#define NPTS  4096   // N == M == 4096
#define KD    64
#define MQ    8      // m-strips: each block walks 512 cols = 4 tiles of 128
#define WALK  4
#define FINF  3.0e38f

typedef float f32x4 __attribute__((ext_vector_type(4)));
typedef float f32x2 __attribute__((ext_vector_type(2)));
typedef short s16x8 __attribute__((ext_vector_type(8)));

__device__ __forceinline__ unsigned int f2bf(float f) {
  // round-to-nearest-even fp32 -> bf16 (inputs finite)
  unsigned int u = __float_as_uint(f);
  u += 0x7FFFu + ((u >> 16) & 1u);
  return u >> 16;
}

__device__ __forceinline__ void stage16(const void* g, void* l) {
  // async global->LDS, 16B/lane; LDS dst = wave-uniform base + lane*16
  __builtin_amdgcn_global_load_lds((const __attribute__((address_space(1))) void*)g,
                                   (__attribute__((address_space(3))) void*)l, 16, 0, 0);
}

// ---------------------------------------------------------------------------
// Prepass: convert X,Y (fp32 [32768][64]) to bf16 packed (uint [32768][32])
// and compute exact fp32 squared norms. 32 threads per row, 2 floats/thread.
// Also zeroes the reduce-phase counter (stream order makes this race-free).
__global__ __launch_bounds__(256)
void prep_kernel(const float* __restrict__ X, const float* __restrict__ Y,
                 unsigned int* __restrict__ Xbf, unsigned int* __restrict__ Ybf,
                 float* __restrict__ x2, float* __restrict__ y2,
                 unsigned int* __restrict__ counter) {
  int gid = blockIdx.x * 256 + threadIdx.x;
  if (gid == 0) *counter = 0;
  int row = gid >> 5;
  int ki  = gid & 31;
  bool isX = row < BATCH * NPTS;
  int r2 = row & (BATCH * NPTS - 1);
  const float* src = isX ? X : Y;
  f32x2 v = *(const f32x2*)(src + (size_t)r2 * KD + ki * 2);
  float s = v[0] * v[0] + v[1] * v[1];
  #pragma unroll
  for (int m = 16; m >= 1; m >>= 1) s += __shfl_xor(s, m, 64);  // stays in 32-lane half
  unsigned int packed = (f2bf(v[1]) << 16) | f2bf(v[0]);
  (isX ? Xbf : Ybf)[r2 * 32 + ki] = packed;
  if (ki == 0) (isX ? x2 : y2)[r2] = s;
}

// ---------------------------------------------------------------------------
// Main: block = (mq, ntile, b). 128 rows x 512 cols (4 m-tiles of 128).
// Waves in 2x2: wave tile 64x64 per m-tile. launch_bounds(256,2): unified
// reg budget 256 (~128 arch + 128 acc) — the (256,3) cap of rounds 3/4 split
// as 84+84 and SPILLED the xf/rm live set to scratch (VGPR_Count=84,
// WRITE_SIZE 96-600 MB). Live set ~130 arch fits under 128+granularity.
// Y double-buffered in LDS via global_load_lds, XOR-swizzled. y2 loads issue
// BEFORE the prefetch so the epilogue's y2 wait is vmcnt(4), not vmcnt(0).
__global__ __launch_bounds__(256, 2)
void chamfer_main(const unsigned short* __restrict__ Xbf,
                  const unsigned short* __restrict__ Ybf,
                  const float* __restrict__ x2g, const float* __restrict__ y2g,
                  float* __restrict__ rowpart,   // [MQ][B*N] min over strip cols (sq)
                  float* __restrict__ colpart) { // [32][B*M] min over ntile rows (sq)
  __shared__ __align__(16) unsigned short Xs[128 * 64];      // 16 KB (reused as l_redf)
  __shared__ __align__(16) unsigned short Ys[2][128 * 64];   // 32 KB
  __shared__ float l_cred[2 * 512];                          // 4 KB: [rowgroup][strip col]

  const int mq = blockIdx.x, ntile = blockIdx.y, b = blockIdx.z;
  const int n0 = ntile * 128;
  const int mbase = mq * 512;
  const int t = threadIdx.x, w = t >> 6, lane = t & 63, c = lane & 15, q = lane >> 4;
  const int wr = (w >> 1) * 64, wc = (w & 1) * 64, rg = w >> 1;

  // staging source offset within a 1KB (8-row) block: row=lane>>3, chunk=(lane&7)^(lane>>3)
  const int l8 = lane >> 3;
  const int lane_off = l8 * 128 + (((lane & 7) ^ l8) << 4);

  const char* Xg  = (const char*)(Xbf + (size_t)(b * NPTS + n0) * KD);
  const char* Yg0 = (const char*)(Ybf + (size_t)(b * NPTS + mbase) * KD);

  // Prologue: stage X tile + Y tile 0 (4 x 1KB per wave each)
  #pragma unroll
  for (int k = 0; k < 4; ++k) {
    int blockoff = (k * 32 + w * 8) * 128;
    int ldsoff   = (k * 256 + w * 64) * 16;
    stage16(Xg  + blockoff + lane_off, (char*)Xs    + ldsoff);
    stage16(Yg0 + blockoff + lane_off, (char*)Ys[0] + ldsoff);
  }

  // x2 fragment (rows wr + i*16 + q*4 + r), fp32, L2-hot. 16 VGPRs.
  const float* x2b = x2g + b * NPTS + n0;
  f32x4 x2r[4];
  #pragma unroll
  for (int i = 0; i < 4; ++i) x2r[i] = *(const f32x4*)(x2b + wr + i * 16 + q * 4);

  __syncthreads();  // drains the global_load_lds (vmcnt 0 at barrier)

  // X fragments -> registers (swizzled ds_read_b128, conflict-free). 32 VGPRs.
  const int cx = c & 7;
  s16x8 xf[4][2];
  #pragma unroll
  for (int i = 0; i < 4; ++i)
    #pragma unroll
    for (int ks = 0; ks < 2; ++ks)
      xf[i][ks] = *(const s16x8*)&Xs[(wr + i * 16 + c) * 64 + ((((ks << 2) + q) ^ cx) << 3)];

  float rm[4][4];
  #pragma unroll
  for (int i = 0; i < 4; ++i)
    #pragma unroll
    for (int r = 0; r < 4; ++r) rm[i][r] = FINF;

  const float* y2b = y2g + b * NPTS + mbase;
  const f32x4 zacc = {0.f, 0.f, 0.f, 0.f};

  #pragma unroll
  for (int tt = 0; tt < WALK; ++tt) {
    const unsigned short* cur = Ys[tt & 1];

    // y2 for this wave's 4 col groups — BEFORE the prefetch (keeps it async).
    float y2c[4];
    #pragma unroll
    for (int j = 0; j < 4; ++j) y2c[j] = y2b[tt * 128 + wc + j * 16 + c];

    if (tt < WALK - 1) {  // async-prefetch next Y tile into the other buffer
      const char* Ygt = Yg0 + (size_t)(tt + 1) * 128 * 128;
      unsigned short* nb = Ys[(tt + 1) & 1];
      #pragma unroll
      for (int k = 0; k < 4; ++k)
        stage16(Ygt + (k * 32 + w * 8) * 128 + lane_off,
                (char*)nb + (k * 256 + w * 64) * 16);
    }

    float cmj[4];
    #pragma unroll
    for (int j = 0; j < 4; ++j) {
      const unsigned short* yrow = &cur[(wc + j * 16 + c) * 64];
      s16x8 yf0 = *(const s16x8*)&yrow[(q ^ cx) << 3];
      s16x8 yf1 = *(const s16x8*)&yrow[((4 + q) ^ cx) << 3];
      f32x4 acc[4];
      #pragma unroll
      for (int i = 0; i < 4; ++i) {
        f32x4 a0 = __builtin_amdgcn_mfma_f32_16x16x32_bf16(xf[i][0], yf0, zacc, 0, 0, 0);
        acc[i] = __builtin_amdgcn_mfma_f32_16x16x32_bf16(xf[i][1], yf1, a0, 0, 0, 0);
      }
      float cm = FINF;
      #pragma unroll
      for (int i = 0; i < 4; ++i)
        #pragma unroll
        for (int r = 0; r < 4; ++r) {
          float v = acc[i][r];
          rm[i][r] = fminf(rm[i][r], fmaf(-2.f, v, y2c[j]));
          cm = fminf(cm, fmaf(-2.f, v, x2r[i][r]));
        }
      // col-min over this wave's 64 rows: reduce across the 4 q-groups
      cm = fminf(cm, __shfl_xor(cm, 16, 64));
      cm = fminf(cm, __shfl_xor(cm, 32, 64));
      cmj[j] = cm;
    }
    // quad q stores col group j==q: one ds_write, 64 consecutive floats/wave
    float cmq = (q == 0) ? cmj[0] : (q == 1) ? cmj[1] : (q == 2) ? cmj[2] : cmj[3];
    l_cred[rg * 512 + tt * 128 + wc + q * 16 + c] = cmq;

    __syncthreads();  // buffer swap barrier (prefetch had MFMA+epilogue to land)
  }

  // Row-min: reduce over the 16 c-lanes within each q-group...
  #pragma unroll
  for (int msk = 1; msk <= 8; msk <<= 1)
    #pragma unroll
    for (int i = 0; i < 4; ++i)
      #pragma unroll
      for (int r = 0; r < 4; ++r)
        rm[i][r] = fminf(rm[i][r], __shfl_xor(rm[i][r], msk, 64));
  // ...then store per-wave row-mins to LDS (literal indices only).
  float* l_redf = (float*)Xs;  // Xs is dead after the prologue xf reads
  if (c == 0) {
    #pragma unroll
    for (int i = 0; i < 4; ++i) {
      f32x4 v = {rm[i][0], rm[i][1], rm[i][2], rm[i][3]};
      *(f32x4*)&l_redf[w * 64 + i * 16 + q * 4] = v;
    }
  }
  __syncthreads();

  if (t < 128) {
    // combine the 2 col-group waves of each row group, add x2, store
    int g = t >> 6, lr = t & 63;
    float v = fminf(l_redf[(g * 2) * 64 + lr], l_redf[(g * 2 + 1) * 64 + lr]);
    rowpart[mq * (BATCH * NPTS) + b * NPTS + n0 + t] = v + x2b[t];
  } else {
    // combine the 2 row groups for each of the 512 strip cols, add y2, store
    float* colrow = colpart + (size_t)(ntile * 8 + b) * NPTS + mbase;
    int ct = t - 128;
    #pragma unroll
    for (int u = 0; u < 4; ++u) {
      int cc = ct + u * 128;
      float v = fminf(l_cred[cc], l_cred[512 + cc]);
      colrow[cc] = v + y2b[cc];
    }
  }
}

// ---------------------------------------------------------------------------
// Final: min over partials, sqrt, mean — self-finalizing (no memset, no 4th
// stream op). 128 blocks; the last block (device-scope ticket) sums the 128
// block partials and writes the scalar output.
__global__ __launch_bounds__(256)
void reduce_kernel(const float* __restrict__ rowpart, const float* __restrict__ colpart,
                   float* __restrict__ partials, unsigned int* __restrict__ counter,
                   float* __restrict__ out) {
  int i = blockIdx.x * 256 + threadIdx.x;
  const int TOT = BATCH * NPTS;
  float rv = FINF;
  #pragma unroll
  for (int s = 0; s < MQ; ++s) rv = fminf(rv, rowpart[s * TOT + i]);
  float s0 = sqrtf(fmaxf(rv, 0.f));
  float cv = FINF;
  #pragma unroll
  for (int nt = 0; nt < 32; ++nt) cv = fminf(cv, colpart[nt * TOT + i]);
  s0 += sqrtf(fmaxf(cv, 0.f));
  #pragma unroll
  for (int m = 32; m >= 1; m >>= 1) s0 += __shfl_xor(s0, m, 64);
  __shared__ float wsum[4];
  if ((threadIdx.x & 63) == 0) wsum[threadIdx.x >> 6] = s0;
  __syncthreads();

  if (threadIdx.x < 64) {  // wave 0 publishes the block partial, then maybe finalizes
    unsigned int ticket = 0;
    if (threadIdx.x == 0) {
      float bsum = wsum[0] + wsum[1] + wsum[2] + wsum[3];
      atomicExch(&partials[blockIdx.x], bsum);  // device-scope visible store
      __threadfence();
      ticket = atomicAdd(counter, 1);
    }
    ticket = __shfl(ticket, 0, 64);
    if (ticket == 127) {  // all 128 partials published
      float v = atomicAdd(&partials[threadIdx.x], 0.0f) +
                atomicAdd(&partials[threadIdx.x + 64], 0.0f);
      #pragma unroll
      for (int m = 32; m >= 1; m >>= 1) v += __shfl_xor(v, m, 64);
      if (threadIdx.x == 0) out[0] = v * (1.0f / (float)TOT);
    }
  }
}

// ---------------------------------------------------------------------------
extern "C" void kernel_launch(void* const* d_in, const int* in_sizes, int n_in,
                              void* d_out, int out_size, void* d_ws, size_t ws_size,
                              hipStream_t stream) {
  const float* X = (const float*)d_in[0];  // [B, N, 64] fp32
  const float* Y = (const float*)d_in[1];  // [B, M, 64] fp32
  float* out = (float*)d_out;

  // Workspace layout (bytes):
  //   Xbf 4MB | Ybf 4MB | x2 128KB | y2 128KB | rowpart 1MB | colpart 4MB
  //   | partials 512B | counter 4B
  char* ws = (char*)d_ws;
  unsigned int* Xbf = (unsigned int*)ws;                       // packed bf16 pairs
  unsigned int* Ybf = (unsigned int*)(ws + (4u << 20));
  float* x2 = (float*)(ws + (8u << 20));
  float* y2 = (float*)(ws + (8u << 20) + (128u << 10));
  float* rowpart = (float*)(ws + (8u << 20) + (256u << 10));
  float* colpart = (float*)(ws + (9u << 20) + (256u << 10));
  float* partials = (float*)(ws + (13u << 20) + (256u << 10));
  unsigned int* counter = (unsigned int*)(partials + 128);

  // Prepass: both inputs, 32 threads/row. Also zeroes `counter`.
  prep_kernel<<<dim3(2 * BATCH * NPTS * 32 / 256), dim3(256), 0, stream>>>(
      X, Y, Xbf, Ybf, x2, y2, counter);

  // Main: (mq=8, ntile=32, b=8) = 2048 blocks, 3 resident/CU (LDS-capped).
  chamfer_main<<<dim3(MQ, 32, 8), dim3(256), 0, stream>>>(
      (const unsigned short*)Xbf, (const unsigned short*)Ybf, x2, y2, rowpart, colpart);

  // Final min/sqrt/mean (self-finalizing via ticket).
  reduce_kernel<<<dim3(BATCH * NPTS / 256), dim3(256), 0, stream>>>(
      rowpart, colpart, partials, counter, out);
}